// Round 1
// baseline (2508.796 us; speedup 1.0000x reference)
//
#include <hip/hip_runtime.h>

#define N_NODES 100000
#define N_EDGES 3200000
#define N_GRAPHS 2048
#define H 64
#define N_LAYERS 3

// ---------------- kernels ----------------

// init: deg=1 (self-loop), zero pooled sums and counts
__global__ void k_init(float* deg, float* sums, float* cnt) {
    int i = blockIdx.x * blockDim.x + threadIdx.x;
    if (i < N_NODES) deg[i] = 1.0f;
    if (i < N_GRAPHS * H) sums[i] = 0.0f;
    if (i < N_GRAPHS) cnt[i] = 0.0f;
}

// degree count over target (col) indices
__global__ void k_deg(const int* __restrict__ col, float* __restrict__ deg) {
    int e = blockIdx.x * blockDim.x + threadIdx.x;
    if (e < N_EDGES) atomicAdd(&deg[col[e]], 1.0f);
}

// dinv = 1/sqrt(deg) in place (deg >= 1 always due to self-loops)
__global__ void k_dinv(float* deg) {
    int i = blockIdx.x * blockDim.x + threadIdx.x;
    if (i < N_NODES) deg[i] = 1.0f / sqrtf(deg[i]);
}

// h = emb[x]
__global__ void k_embed(const int* __restrict__ x, const float* __restrict__ emb,
                        float* __restrict__ h) {
    int i = blockIdx.x * blockDim.x + threadIdx.x;
    if (i >= N_NODES * H) return;
    int n = i >> 6, c = i & 63;
    h[i] = emb[x[n] * H + c];
}

// t = dinv[n] * (h @ W); also agg = t (self-loop contribution, pre-final-scale)
// block = 256 threads = 4 nodes x 64 channels
__global__ void k_linear(const float* __restrict__ h, const float* __restrict__ W,
                         const float* __restrict__ dinv,
                         float* __restrict__ t, float* __restrict__ agg) {
    __shared__ float sW[H * H];
    __shared__ float sh[4][H];
    int tid = threadIdx.x;
    for (int i = tid; i < H * H; i += 256) sW[i] = W[i];
    int r = tid >> 6, c = tid & 63;
    int n = blockIdx.x * 4 + r;
    sh[r][c] = (n < N_NODES) ? h[n * H + c] : 0.0f;
    __syncthreads();
    if (n < N_NODES) {
        float acc = 0.0f;
#pragma unroll
        for (int k = 0; k < H; ++k) acc += sh[r][k] * sW[k * H + c];
        float v = acc * dinv[n];
        t[n * H + c] = v;
        agg[n * H + c] = v;  // self-loop init: agg[n] = t'[n]
    }
}

// edge scatter: agg[col] += t[row]  (64 lanes = 64 channels per edge)
__global__ void k_scatter(const int* __restrict__ row, const int* __restrict__ col,
                          const float* __restrict__ t, float* __restrict__ agg) {
    int gid = blockIdx.x * blockDim.x + threadIdx.x;
    int lane = gid & 63;
    int e = gid >> 6;
    int stride = (gridDim.x * blockDim.x) >> 6;
    for (; e < N_EDGES; e += stride) {
        int r = row[e];
        int cN = col[e];
        atomicAdd(&agg[cN * H + lane], t[r * H + lane]);
    }
}

// h_new = relu(dinv[n]*agg + b); h = (layer==0) ? h_new : h + h_new
__global__ void k_finalize(const float* __restrict__ agg, const float* __restrict__ dinv,
                           const float* __restrict__ b, float* __restrict__ h, int layer) {
    int i = blockIdx.x * blockDim.x + threadIdx.x;
    if (i >= N_NODES * H) return;
    int n = i >> 6, c = i & 63;
    float v = fmaxf(agg[i] * dinv[n] + b[c], 0.0f);
    h[i] = (layer == 0) ? v : h[i] + v;
}

// global mean-pool accumulation
__global__ void k_pool(const float* __restrict__ h, const int* __restrict__ batch,
                       float* __restrict__ sums, float* __restrict__ cnt) {
    int i = blockIdx.x * blockDim.x + threadIdx.x;
    if (i >= N_NODES * H) return;
    int n = i >> 6, c = i & 63;
    int g = batch[n];
    atomicAdd(&sums[g * H + c], h[i]);
    if (c == 0) atomicAdd(&cnt[g], 1.0f);
}

// predictor MLP: one block (64 threads) per graph
__global__ void k_mlp(const float* __restrict__ sums, const float* __restrict__ cnt,
                      const float* __restrict__ w1, const float* __restrict__ b1,
                      const float* __restrict__ w2, const float* __restrict__ b2,
                      const float* __restrict__ w3, const float* __restrict__ b3,
                      float* __restrict__ out) {
    __shared__ float sg[H];
    __shared__ float s1[32];
    __shared__ float s2[16];
    int g = blockIdx.x, tid = threadIdx.x;
    float inv = 1.0f / fmaxf(cnt[g], 1.0f);
    sg[tid] = sums[g * H + tid] * inv;
    __syncthreads();
    if (tid < 32) {
        float acc = b1[tid];
#pragma unroll
        for (int k = 0; k < H; ++k) acc += sg[k] * w1[k * 32 + tid];
        s1[tid] = fmaxf(acc, 0.0f);
    }
    __syncthreads();
    if (tid < 16) {
        float acc = b2[tid];
#pragma unroll
        for (int k = 0; k < 32; ++k) acc += s1[k] * w2[k * 16 + tid];
        s2[tid] = fmaxf(acc, 0.0f);
    }
    __syncthreads();
    if (tid == 0) {
        float acc = b3[0];
#pragma unroll
        for (int k = 0; k < 16; ++k) acc += s2[k] * w3[k];
        out[g] = acc;
    }
}

// ---------------- launch ----------------

extern "C" void kernel_launch(void* const* d_in, const int* in_sizes, int n_in,
                              void* d_out, int out_size, void* d_ws, size_t ws_size,
                              hipStream_t stream) {
    const int*   x      = (const int*)d_in[0];
    const int*   eidx   = (const int*)d_in[1];   // (2, E): row = eidx, col = eidx + E
    const int*   batch  = (const int*)d_in[2];
    const float* emb    = (const float*)d_in[3];
    const float* conv_w = (const float*)d_in[4]; // (3, 64, 64)
    const float* conv_b = (const float*)d_in[5]; // (3, 64)
    const float* w1     = (const float*)d_in[6];
    const float* b1     = (const float*)d_in[7];
    const float* w2     = (const float*)d_in[8];
    const float* b2     = (const float*)d_in[9];
    const float* w3     = (const float*)d_in[10];
    const float* b3     = (const float*)d_in[11];
    float* out = (float*)d_out;

    const int* row = eidx;
    const int* col = eidx + N_EDGES;

    // workspace layout (floats), 256B-aligned chunks
    float* ws   = (float*)d_ws;
    size_t off  = 0;
    float* dinv = ws + off; off += ((N_NODES + 63) & ~63);         // deg -> dinv in place
    float* h    = ws + off; off += (size_t)N_NODES * H;
    float* t    = ws + off; off += (size_t)N_NODES * H;
    float* agg  = ws + off; off += (size_t)N_NODES * H;
    float* sums = ws + off; off += (size_t)N_GRAPHS * H;
    float* cnt  = ws + off; off += N_GRAPHS;

    const int B = 256;
    const int gNH   = (N_NODES * H + B - 1) / B;   // 25000
    const int gN    = (N_NODES + B - 1) / B;       // 391
    const int gE    = (N_EDGES + B - 1) / B;       // 12500
    const int gInit = (N_GRAPHS * H + B - 1) / B;  // 512 (covers N_GRAPHS*H > N_NODES? no)
    const int gInitAll = ((N_NODES > N_GRAPHS * H ? N_NODES : N_GRAPHS * H) + B - 1) / B;

    hipLaunchKernelGGL(k_init, dim3(gInitAll), dim3(B), 0, stream, dinv, sums, cnt);
    hipLaunchKernelGGL(k_deg, dim3(gE), dim3(B), 0, stream, col, dinv);
    hipLaunchKernelGGL(k_dinv, dim3(gN), dim3(B), 0, stream, dinv);
    hipLaunchKernelGGL(k_embed, dim3(gNH), dim3(B), 0, stream, x, emb, h);

    const int gScatter = 200000;  // 800k waves, 4 edges per wave
    for (int layer = 0; layer < N_LAYERS; ++layer) {
        hipLaunchKernelGGL(k_linear, dim3((N_NODES + 3) / 4), dim3(B), 0, stream,
                           h, conv_w + (size_t)layer * H * H, dinv, t, agg);
        hipLaunchKernelGGL(k_scatter, dim3(gScatter), dim3(B), 0, stream, row, col, t, agg);
        hipLaunchKernelGGL(k_finalize, dim3(gNH), dim3(B), 0, stream,
                           agg, dinv, conv_b + (size_t)layer * H, h, layer);
    }

    hipLaunchKernelGGL(k_pool, dim3(gNH), dim3(B), 0, stream, h, batch, sums, cnt);
    hipLaunchKernelGGL(k_mlp, dim3(N_GRAPHS), dim3(64), 0, stream,
                       sums, cnt, w1, b1, w2, b2, w3, b3, out);

    (void)in_sizes; (void)n_in; (void)out_size; (void)ws_size; (void)gInit;
}

// Round 2
// 1100.005 us; speedup vs baseline: 2.2807x; 2.2807x over previous
//
#include <hip/hip_runtime.h>

#define N_NODES 100000
#define N_EDGES 3200000
#define N_GRAPHS 2048
#define H 64
#define N_LAYERS 3

#define SCAN_ELEMS 1024
#define NB_SCAN ((N_NODES + SCAN_ELEMS - 1) / SCAN_ELEMS)  // 98

// ---------------- kernels ----------------

// zero int degree histogram, pooled sums, counts
__global__ void k_init(int* degi, float* sums, float* cnt) {
    int i = blockIdx.x * blockDim.x + threadIdx.x;
    if (i < N_NODES) degi[i] = 0;
    if (i < N_GRAPHS * H) sums[i] = 0.0f;
    if (i < N_GRAPHS) cnt[i] = 0.0f;
}

// degree histogram over target (col) indices
__global__ void k_hist(const int* __restrict__ col, int* __restrict__ degi) {
    int e = blockIdx.x * blockDim.x + threadIdx.x;
    if (e < N_EDGES) atomicAdd(&degi[col[e]], 1);
}

// exclusive scan, stage 1: each block scans 1024 elements (4/thread)
__global__ void k_scan1(const int* __restrict__ in, int* __restrict__ out,
                        int* __restrict__ bsums) {
    __shared__ int s[256];
    int b = blockIdx.x, tid = threadIdx.x;
    int base = b * SCAN_ELEMS + tid * 4;
    int v0 = (base + 0 < N_NODES) ? in[base + 0] : 0;
    int v1 = (base + 1 < N_NODES) ? in[base + 1] : 0;
    int v2 = (base + 2 < N_NODES) ? in[base + 2] : 0;
    int v3 = (base + 3 < N_NODES) ? in[base + 3] : 0;
    int tsum = v0 + v1 + v2 + v3;
    s[tid] = tsum;
    __syncthreads();
    for (int off = 1; off < 256; off <<= 1) {
        int x = (tid >= off) ? s[tid - off] : 0;
        __syncthreads();
        s[tid] += x;
        __syncthreads();
    }
    int excl = s[tid] - tsum;
    if (base + 0 < N_NODES) out[base + 0] = excl;
    if (base + 1 < N_NODES) out[base + 1] = excl + v0;
    if (base + 2 < N_NODES) out[base + 2] = excl + v0 + v1;
    if (base + 3 < N_NODES) out[base + 3] = excl + v0 + v1 + v2;
    if (tid == 0) bsums[b] = s[255];
}

// stage 2: scan the 98 block sums (single block, 128 threads)
__global__ void k_scan2(int* __restrict__ bsums, int* __restrict__ boffs) {
    __shared__ int s[128];
    int tid = threadIdx.x;
    int v = (tid < NB_SCAN) ? bsums[tid] : 0;
    s[tid] = v;
    __syncthreads();
    for (int off = 1; off < 128; off <<= 1) {
        int x = (tid >= off) ? s[tid - off] : 0;
        __syncthreads();
        s[tid] += x;
        __syncthreads();
    }
    if (tid < NB_SCAN) boffs[tid] = s[tid] - v;  // exclusive
}

// stage 3: add block offsets -> row_start; init cursor; dinv = rsqrt(deg+1)
__global__ void k_scan3(const int* __restrict__ scanned, const int* __restrict__ boffs,
                        const int* __restrict__ degi, int* __restrict__ row_start,
                        int* __restrict__ cursor, float* __restrict__ dinv) {
    int i = blockIdx.x * blockDim.x + threadIdx.x;
    if (i >= N_NODES) return;
    int rs = scanned[i] + boffs[i / SCAN_ELEMS];
    row_start[i] = rs;
    cursor[i] = rs;
    dinv[i] = rsqrtf((float)(degi[i] + 1));  // +1 self-loop
}

// reorder edges into CSR-by-col buckets
__global__ void k_reorder(const int* __restrict__ row, const int* __restrict__ col,
                          int* __restrict__ cursor, int* __restrict__ sorted_row) {
    int e = blockIdx.x * blockDim.x + threadIdx.x;
    if (e >= N_EDGES) return;
    int pos = atomicAdd(&cursor[col[e]], 1);
    sorted_row[pos] = row[e];
}

// h = emb[x]
__global__ void k_embed(const int* __restrict__ x, const float* __restrict__ emb,
                        float* __restrict__ h) {
    int i = blockIdx.x * blockDim.x + threadIdx.x;
    if (i >= N_NODES * H) return;
    int n = i >> 6, c = i & 63;
    h[i] = emb[x[n] * H + c];
}

// t' = dinv[n] * (h @ W)   (block = 4 nodes x 64 channels)
__global__ void k_linear(const float* __restrict__ h, const float* __restrict__ W,
                         const float* __restrict__ dinv, float* __restrict__ t) {
    __shared__ float sW[H * H];
    __shared__ float sh[4][H];
    int tid = threadIdx.x;
    for (int i = tid; i < H * H; i += 256) sW[i] = W[i];
    int r = tid >> 6, c = tid & 63;
    int n = blockIdx.x * 4 + r;
    sh[r][c] = (n < N_NODES) ? h[n * H + c] : 0.0f;
    __syncthreads();
    if (n < N_NODES) {
        float acc = 0.0f;
#pragma unroll
        for (int k = 0; k < H; ++k) acc += sh[r][k] * sW[k * H + c];
        t[n * H + c] = acc * dinv[n];
    }
}

// fused gather + finalize: one wave per node, lane = channel
// acc = t'[n] (self loop) + sum_e t'[row[e]];  h_new = relu(dinv[n]*acc + b)
__global__ void k_gather(const int* __restrict__ sorted_row, const int* __restrict__ row_start,
                         const int* __restrict__ degi, const float* __restrict__ t,
                         const float* __restrict__ dinv, const float* __restrict__ b,
                         float* __restrict__ h, int layer) {
    int gid = blockIdx.x * blockDim.x + threadIdx.x;
    int n = gid >> 6;
    int lane = gid & 63;
    if (n >= N_NODES) return;
    int start = row_start[n];
    int d = degi[n];
    float acc = t[n * H + lane];  // self-loop term
    int e = 0;
    for (; e + 4 <= d; e += 4) {
        int r0 = sorted_row[start + e + 0];
        int r1 = sorted_row[start + e + 1];
        int r2 = sorted_row[start + e + 2];
        int r3 = sorted_row[start + e + 3];
        float a0 = t[r0 * H + lane];
        float a1 = t[r1 * H + lane];
        float a2 = t[r2 * H + lane];
        float a3 = t[r3 * H + lane];
        acc += a0 + a1 + a2 + a3;
    }
    for (; e < d; ++e) acc += t[sorted_row[start + e] * H + lane];
    float v = fmaxf(acc * dinv[n] + b[lane], 0.0f);
    h[n * H + lane] = (layer == 0) ? v : h[n * H + lane] + v;
}

// global mean-pool accumulation
__global__ void k_pool(const float* __restrict__ h, const int* __restrict__ batch,
                       float* __restrict__ sums, float* __restrict__ cnt) {
    int i = blockIdx.x * blockDim.x + threadIdx.x;
    if (i >= N_NODES * H) return;
    int n = i >> 6, c = i & 63;
    int g = batch[n];
    atomicAdd(&sums[g * H + c], h[i]);
    if (c == 0) atomicAdd(&cnt[g], 1.0f);
}

// predictor MLP: one block (64 threads) per graph
__global__ void k_mlp(const float* __restrict__ sums, const float* __restrict__ cnt,
                      const float* __restrict__ w1, const float* __restrict__ b1,
                      const float* __restrict__ w2, const float* __restrict__ b2,
                      const float* __restrict__ w3, const float* __restrict__ b3,
                      float* __restrict__ out) {
    __shared__ float sg[H];
    __shared__ float s1[32];
    __shared__ float s2[16];
    int g = blockIdx.x, tid = threadIdx.x;
    float inv = 1.0f / fmaxf(cnt[g], 1.0f);
    sg[tid] = sums[g * H + tid] * inv;
    __syncthreads();
    if (tid < 32) {
        float acc = b1[tid];
#pragma unroll
        for (int k = 0; k < H; ++k) acc += sg[k] * w1[k * 32 + tid];
        s1[tid] = fmaxf(acc, 0.0f);
    }
    __syncthreads();
    if (tid < 16) {
        float acc = b2[tid];
#pragma unroll
        for (int k = 0; k < 32; ++k) acc += s1[k] * w2[k * 16 + tid];
        s2[tid] = fmaxf(acc, 0.0f);
    }
    __syncthreads();
    if (tid == 0) {
        float acc = b3[0];
#pragma unroll
        for (int k = 0; k < 16; ++k) acc += s2[k] * w3[k];
        out[g] = acc;
    }
}

// ---------------- launch ----------------

extern "C" void kernel_launch(void* const* d_in, const int* in_sizes, int n_in,
                              void* d_out, int out_size, void* d_ws, size_t ws_size,
                              hipStream_t stream) {
    const int*   x      = (const int*)d_in[0];
    const int*   eidx   = (const int*)d_in[1];   // (2, E): row = eidx, col = eidx + E
    const int*   batch  = (const int*)d_in[2];
    const float* emb    = (const float*)d_in[3];
    const float* conv_w = (const float*)d_in[4]; // (3, 64, 64)
    const float* conv_b = (const float*)d_in[5]; // (3, 64)
    const float* w1     = (const float*)d_in[6];
    const float* b1     = (const float*)d_in[7];
    const float* w2     = (const float*)d_in[8];
    const float* b2     = (const float*)d_in[9];
    const float* w3     = (const float*)d_in[10];
    const float* b3     = (const float*)d_in[11];
    float* out = (float*)d_out;

    const int* row = eidx;
    const int* col = eidx + N_EDGES;

    // workspace layout (4-byte units)
    char* wsb = (char*)d_ws;
    size_t off = 0;
    auto alloc = [&](size_t elems) { void* p = wsb + off; off += ((elems * 4 + 255) & ~(size_t)255); return p; };
    int*   degi       = (int*)alloc(N_NODES);
    int*   scanned    = (int*)alloc(N_NODES);
    int*   bsums      = (int*)alloc(NB_SCAN);
    int*   boffs      = (int*)alloc(NB_SCAN);
    int*   row_start  = (int*)alloc(N_NODES);
    int*   cursor     = (int*)alloc(N_NODES);
    int*   sorted_row = (int*)alloc(N_EDGES);
    float* dinv       = (float*)alloc(N_NODES);
    float* h          = (float*)alloc((size_t)N_NODES * H);
    float* t          = (float*)alloc((size_t)N_NODES * H);
    float* sums       = (float*)alloc((size_t)N_GRAPHS * H);
    float* cnt        = (float*)alloc(N_GRAPHS);

    const int B = 256;
    const int gNH = (N_NODES * H + B - 1) / B;  // 25000
    const int gN  = (N_NODES + B - 1) / B;      // 391
    const int gE  = (N_EDGES + B - 1) / B;      // 12500
    const int gInitAll = ((N_GRAPHS * H > N_NODES ? N_GRAPHS * H : N_NODES) + B - 1) / B;

    hipLaunchKernelGGL(k_init, dim3(gInitAll), dim3(B), 0, stream, degi, sums, cnt);
    hipLaunchKernelGGL(k_hist, dim3(gE), dim3(B), 0, stream, col, degi);
    hipLaunchKernelGGL(k_scan1, dim3(NB_SCAN), dim3(256), 0, stream, degi, scanned, bsums);
    hipLaunchKernelGGL(k_scan2, dim3(1), dim3(128), 0, stream, bsums, boffs);
    hipLaunchKernelGGL(k_scan3, dim3(gN), dim3(B), 0, stream, scanned, boffs, degi,
                       row_start, cursor, dinv);
    hipLaunchKernelGGL(k_reorder, dim3(gE), dim3(B), 0, stream, row, col, cursor, sorted_row);
    hipLaunchKernelGGL(k_embed, dim3(gNH), dim3(B), 0, stream, x, emb, h);

    for (int layer = 0; layer < N_LAYERS; ++layer) {
        hipLaunchKernelGGL(k_linear, dim3((N_NODES + 3) / 4), dim3(B), 0, stream,
                           h, conv_w + (size_t)layer * H * H, dinv, t);
        hipLaunchKernelGGL(k_gather, dim3(gNH), dim3(B), 0, stream,
                           sorted_row, row_start, degi, t, dinv,
                           conv_b + (size_t)layer * H, h, layer);
    }

    hipLaunchKernelGGL(k_pool, dim3(gNH), dim3(B), 0, stream, h, batch, sums, cnt);
    hipLaunchKernelGGL(k_mlp, dim3(N_GRAPHS), dim3(64), 0, stream,
                       sums, cnt, w1, b1, w2, b2, w3, b3, out);

    (void)in_sizes; (void)n_in; (void)out_size; (void)ws_size;
}